// Round 3
// baseline (485.264 us; speedup 1.0000x reference)
//
#include <hip/hip_runtime.h>
#include <hip/hip_fp16.h>
#include <cstdint>

typedef _Float16 f16;
typedef __attribute__((ext_vector_type(8))) _Float16 half8;
typedef __attribute__((ext_vector_type(4))) float floatx4;
typedef __attribute__((ext_vector_type(16))) float floatx16;

#define CC 1024
#define DD 128
#define RRR 64
#define BBATCH 4
#define NNN 4096   // H*W

#define BM 128
#define BN 128
#define BK 64

__device__ __forceinline__ void gl_lds16(const void* g, void* l) {
  __builtin_amdgcn_global_load_lds(
      (__attribute__((address_space(1))) void*)(uintptr_t)g,
      (__attribute__((address_space(3))) void*)l, 16, 0, 0);
}

// ---------------- GEMM: C[M,N] = A[M,K] * B[N,K]^T  (f16 in, f32 acc, f16 out) ----------------
// 128x128 tile, 4 waves, m97-style single-buffer structure (~900 TF ceiling).
// Kept for: QK-proj (small N) and ws-constrained fallback.
template<int EPI>
__global__ __launch_bounds__(256)
void gemm_bt(const f16* __restrict__ A, const f16* __restrict__ Bp, f16* __restrict__ Cout,
             const float* __restrict__ bias, int N, int K,
             int lda, int ldb, int ldc, size_t sA, size_t sB, size_t sC)
{
  __shared__ __align__(16) f16 S[2 * BM * BK];      // 32 KiB
  f16* As = S;
  f16* Bs = S + BM * BK;

  const int z = blockIdx.z;
  const int tid  = threadIdx.x;
  const int lane = tid & 63;
  const int wave = tid >> 6;
  const int m0 = blockIdx.y * BM;
  const int n0 = blockIdx.x * BN;
  const int wm = (wave >> 1) * 64;
  const int wn = (wave & 1) * 64;
  const int l31 = lane & 31;
  const int hi  = lane >> 5;
  const int rs  = lane & 7;

  const f16* Ab = A  + (size_t)z * sA + (size_t)m0 * lda;
  const f16* Bb = Bp + (size_t)z * sB + (size_t)n0 * ldb;

  floatx16 acc[2][2];
#pragma unroll
  for (int i = 0; i < 2; ++i)
#pragma unroll
    for (int j = 0; j < 2; ++j)
#pragma unroll
      for (int r = 0; r < 16; ++r)
        acc[i][j][r] = 0.f;

  int srow[4], ssrc[4];
#pragma unroll
  for (int r = 0; r < 4; ++r) {
    const int gi = r * 256 + tid;
    const int row = gi >> 3;
    const int gc  = gi & 7;
    srow[r] = row;
    ssrc[r] = ((gc ^ (row & 7)) << 3);
  }

  for (int k0 = 0; k0 < K; k0 += BK) {
#pragma unroll
    for (int r = 0; r < 4; ++r) {
      gl_lds16(Ab + (size_t)srow[r] * lda + k0 + ssrc[r], As + (size_t)(r * 256 + tid) * 8);
      gl_lds16(Bb + (size_t)srow[r] * ldb + k0 + ssrc[r], Bs + (size_t)(r * 256 + tid) * 8);
    }
    __syncthreads();

#pragma unroll
    for (int kk = 0; kk < BK; kk += 16) {
      const int gr = (((kk >> 3) + hi) ^ rs) << 3;
      half8 af[2], bfr[2];
#pragma unroll
      for (int i = 0; i < 2; ++i)
        af[i] = *(const half8*)(As + (wm + i * 32 + l31) * BK + gr);
#pragma unroll
      for (int j = 0; j < 2; ++j)
        bfr[j] = *(const half8*)(Bs + (wn + j * 32 + l31) * BK + gr);
#pragma unroll
      for (int i = 0; i < 2; ++i)
#pragma unroll
        for (int j = 0; j < 2; ++j)
          acc[i][j] = __builtin_amdgcn_mfma_f32_32x32x16_f16(af[i], bfr[j], acc[i][j], 0, 0, 0);
    }
    __syncthreads();
  }

  // epilogue: repack through LDS (granule-swizzled), then 16B coalesced stores
  f16* Ch = Cout + (size_t)z * sC;
  f16* Ct = S;   // 128x128 f16 = 32 KiB
#pragma unroll
  for (int i = 0; i < 2; ++i)
#pragma unroll
    for (int j = 0; j < 2; ++j)
#pragma unroll
      for (int r = 0; r < 16; ++r) {
        const int rl = wm + i * 32 + (r & 3) + 8 * (r >> 2) + 4 * hi;
        const int cl = wn + j * 32 + l31;
        const float v = acc[i][j][r];
        f16 h;
        if constexpr (EPI == 0)      h = (f16)v;
        else if constexpr (EPI == 1) h = (f16)(v + bias[m0 + rl]);
        else if constexpr (EPI == 2) h = (f16)(v + bias[n0 + cl]);
        else                         h = (f16)(1.0f / (1.0f + __expf(-v)));
        Ct[rl * BN + ((((cl >> 3) ^ (rl & 7)) << 3) | (cl & 7))] = h;
      }
  __syncthreads();
#pragma unroll
  for (int p = 0; p < 8; ++p) {
    const int idx = p * 256 + tid;
    const int rl = idx >> 4;
    const int g  = idx & 15;
    half8 vv = *(const half8*)(Ct + rl * BN + ((g ^ (rl & 7)) << 3));
    *(half8*)(Ch + (size_t)(m0 + rl) * ldc + n0 + g * 8) = vv;
  }
}

// ---------------- 256x256 / BK=64 phase-pipelined GEMM (m201 8-phase template) ----------------
// C[M,N] = A[M,K]*B[N,K]^T, f16 in / f32 acc / f16 out. 512 threads = 8 waves (2M x 4N),
// per-wave output 128x64 via mfma_f32_16x16x32_f16 (8 m-sub x 4 n-sub x 2 k-steps).
// ROUND-3 restructure: per phase, ds_reads issue BEFORE bar1 (LDS pipe drains them during
// the barrier wait and other waves' MFMA window) -> LDS/MFMA pipe overlap instead of the
// measured full serialization (r2: 5360 cyc/K-tile = reads+writes+MFMA summed).
// Readiness chain: tile t+1's vmcnt+barrier sits at END of tile t's P3, so P0 reads can
// issue immediately post-barrier. Requires 2-tile-deep prefetch: P3 stages tile t+2 into
// buffer cur (safe: cur's reads all completed at P2-bar2), then vmcnt(8) keeps those 8
// loads in flight across the wait. Never vmcnt(0) in steady state.
#define G8_STAGE(MATG, MIDX, LD, H, KT, BUF) do {                                   \
    gl_lds16(MATG + (size_t)((H) * 128 + srow) * (LD) + (KT) * 64 + soff,           \
             &S[BUF][MIDX][(H) * 8192 + tid * 8]);                                  \
    gl_lds16(MATG + (size_t)((H) * 128 + 64 + srow) * (LD) + (KT) * 64 + soff,      \
             &S[BUF][MIDX][(H) * 8192 + 4096 + tid * 8]);                           \
  } while (0)

#define G8_LDA(MA) do {                                                             \
    _Pragma("unroll") for (int ms = 0; ms < 4; ++ms)                                \
    _Pragma("unroll") for (int ks = 0; ks < 2; ++ks)                                \
      af[ms * 2 + ks] = *(const half8*)(Ac + aRow + (MA) * 4096 + ms * 1024 + sws[ks]); \
  } while (0)

#define G8_LDB(NH) do {                                                             \
    _Pragma("unroll") for (int ns = 0; ns < 2; ++ns)                                \
    _Pragma("unroll") for (int ks = 0; ks < 2; ++ks)                                \
      bf[NH][ns * 2 + ks] = *(const half8*)(Bc + bRow + (NH) * 2048 + ns * 1024 + sws[ks]); \
  } while (0)

#define G8_MFMA(MA, NH) do {                                                        \
    __builtin_amdgcn_s_setprio(1);                                                  \
    _Pragma("unroll") for (int ms = 0; ms < 4; ++ms)                                \
    _Pragma("unroll") for (int ns = 0; ns < 2; ++ns)                                \
    _Pragma("unroll") for (int ks = 0; ks < 2; ++ks)                                \
      acc[(MA) * 4 + ms][(NH) * 2 + ns] = __builtin_amdgcn_mfma_f32_16x16x32_f16(   \
          af[ms * 2 + ks], bf[NH][ns * 2 + ks], acc[(MA) * 4 + ms][(NH) * 2 + ns], 0, 0, 0); \
    __builtin_amdgcn_s_setprio(0);                                                  \
  } while (0)

template<int EPI>   // 0 = plain, 1 = + row bias, 3 = sigmoid
__global__ __launch_bounds__(512, 2)
void gemm8p(const f16* __restrict__ A, const f16* __restrict__ Bp, f16* __restrict__ Cout,
            const float* __restrict__ bias, int K,
            int lda, int ldb, int ldc, size_t sA, size_t sB, size_t sC)
{
  __shared__ __align__(16) f16 S[2][2][16384];   // 128 KiB

  const int tid  = threadIdx.x;
  const int lane = tid & 63;
  const int wave = tid >> 6;       // 0..7
  const int wm   = wave >> 2;      // 0..1 (M)
  const int wn   = wave & 3;       // 0..3 (N)
  const int l15  = lane & 15;
  const int lk   = lane >> 4;      // 0..3 (k-group)
  const int z    = blockIdx.z;
  const int m0   = blockIdx.y * 256;
  const int n0   = blockIdx.x * 256;

  const f16* Ag = A  + (size_t)z * sA + (size_t)m0 * lda;
  const f16* Bg = Bp + (size_t)z * sB + (size_t)n0 * ldb;

  // staging: thread covers granule tid&7 of row tid>>3 (+64/+128 via H/second load)
  const int srow = tid >> 3;                        // 0..63
  const int soff = (((tid & 7) ^ (srow & 7)) << 3); // pre-swizzled global k-offset (f16 units)

  // ds_read un-swizzle per lane: granule = ks*4 + lk, row&7 = l15&7
  int sws[2];
#pragma unroll
  for (int ks = 0; ks < 2; ++ks) sws[ks] = (((ks * 4 + lk) ^ (l15 & 7)) << 3);
  const int aRow = (wm * 128 + l15) * 64;
  const int bRow = (wn * 64 + l15) * 64;

  floatx4 acc[8][4];
#pragma unroll
  for (int i = 0; i < 8; ++i)
#pragma unroll
    for (int j = 0; j < 4; ++j)
#pragma unroll
      for (int r = 0; r < 4; ++r) acc[i][j][r] = 0.f;

  half8 af[8], bf[2][4];

  const int NT = K >> 6;

  // prologue: tiles 0 and 1 fully issued (2-deep prefetch)
  G8_STAGE(Ag, 0, lda, 0, 0, 0);
  G8_STAGE(Bg, 1, ldb, 0, 0, 0);
  G8_STAGE(Ag, 0, lda, 1, 0, 0);
  G8_STAGE(Bg, 1, ldb, 1, 0, 0);
  if (NT > 1) {
    G8_STAGE(Ag, 0, lda, 0, 1, 1);
    G8_STAGE(Bg, 1, ldb, 0, 1, 1);
    G8_STAGE(Ag, 0, lda, 1, 1, 1);
    G8_STAGE(Bg, 1, ldb, 1, 1, 1);
    asm volatile("s_waitcnt vmcnt(8)" ::: "memory");   // tile 0 landed; tile 1 in flight
  } else {
    asm volatile("s_waitcnt vmcnt(0)" ::: "memory");
  }
  __builtin_amdgcn_s_barrier();
  __builtin_amdgcn_sched_barrier(0);

  for (int t = 0; t < NT; ++t) {
    const int cur = t & 1;
    const f16* Ac = &S[cur][0][0];
    const f16* Bc = &S[cur][1][0];

    // ---- P0: reads for Q(0,0) issue pre-barrier; MFMA after lgkm wait
    G8_LDA(0); G8_LDB(0);
    __builtin_amdgcn_s_barrier();
    asm volatile("s_waitcnt lgkmcnt(0)" ::: "memory");
    __builtin_amdgcn_sched_barrier(0);
    G8_MFMA(0, 0);
    __builtin_amdgcn_s_barrier();

    // ---- P1: reads for Q(0,1)
    G8_LDB(1);
    __builtin_amdgcn_s_barrier();
    asm volatile("s_waitcnt lgkmcnt(0)" ::: "memory");
    __builtin_amdgcn_sched_barrier(0);
    G8_MFMA(0, 1);
    __builtin_amdgcn_s_barrier();

    // ---- P2: reads for Q(1,1)
    G8_LDA(1);
    __builtin_amdgcn_s_barrier();
    asm volatile("s_waitcnt lgkmcnt(0)" ::: "memory");
    __builtin_amdgcn_sched_barrier(0);
    G8_MFMA(1, 1);
    __builtin_amdgcn_s_barrier();
    // after this barrier: ALL waves' reads of buffer cur are complete -> cur is writable

    // ---- P3: stage tile t+2 into cur; reg-only MFMA overlaps load flight;
    // ----     readiness wait+barrier for tile t+1 closes the phase
    if (t + 2 < NT) {
      G8_STAGE(Ag, 0, lda, 0, t + 2, cur);
      G8_STAGE(Bg, 1, ldb, 0, t + 2, cur);
      G8_STAGE(Ag, 0, lda, 1, t + 2, cur);
      G8_STAGE(Bg, 1, ldb, 1, t + 2, cur);
      G8_MFMA(1, 0);
      asm volatile("s_waitcnt vmcnt(8)" ::: "memory");  // t+1 landed; t+2 in flight
      __builtin_amdgcn_s_barrier();
      __builtin_amdgcn_sched_barrier(0);
    } else if (t + 1 < NT) {
      G8_MFMA(1, 0);
      asm volatile("s_waitcnt vmcnt(0)" ::: "memory");  // tail: drain t+1
      __builtin_amdgcn_s_barrier();
      __builtin_amdgcn_sched_barrier(0);
    } else {
      G8_MFMA(1, 0);
      // last tile: P2-bar2 already fenced all LDS reads; epilogue follows
    }
  }

  // epilogue: repack (granule-swizzled) through LDS, 16B coalesced stores
  // C/D 16x16: col = lane&15, row = (lane>>4)*4 + reg  [m89/m91 verified, dtype-indep]
  f16* Ct = &S[0][0][0];   // 256x256 f16 = 128 KiB
  f16* Ch = Cout + (size_t)z * sC;
#pragma unroll
  for (int mi = 0; mi < 8; ++mi)
#pragma unroll
    for (int ni = 0; ni < 4; ++ni)
#pragma unroll
      for (int r = 0; r < 4; ++r) {
        const int rl = wm * 128 + mi * 16 + lk * 4 + r;
        const int cl = wn * 64 + ni * 16 + l15;
        const float v = acc[mi][ni][r];
        f16 h;
        if constexpr (EPI == 1)      h = (f16)(v + bias[m0 + rl]);
        else if constexpr (EPI == 3) h = (f16)(1.0f / (1.0f + __expf(-v)));
        else                         h = (f16)v;
        Ct[rl * 256 + ((((cl >> 3) ^ (rl & 7)) << 3) | (cl & 7))] = h;
      }
  asm volatile("s_waitcnt lgkmcnt(0)" ::: "memory");
  __builtin_amdgcn_s_barrier();
#pragma unroll
  for (int p = 0; p < 16; ++p) {
    const int idx = p * 512 + tid;
    const int rl = idx >> 5;
    const int g  = idx & 31;
    half8 vv = *(const half8*)(Ct + rl * 256 + ((g ^ (rl & 7)) << 3));
    *(half8*)(Ch + (size_t)(m0 + rl) * ldc + n0 + g * 8) = vv;
  }
}

#undef G8_STAGE
#undef G8_LDA
#undef G8_LDB
#undef G8_MFMA

// ---------------- weights f32->f16 + bias concat, one dispatch ----------------
__global__ __launch_bounds__(256)
void prep(const float* __restrict__ Wq, const float* __restrict__ Wk, const float* __restrict__ Wv,
          const float* __restrict__ bq, const float* __restrict__ bk,
          f16* __restrict__ WQKb, f16* __restrict__ Wvb, float* __restrict__ bqk)
{
  const int NV = CC * CC;
  const int NQ = DD * CC;
  int i = blockIdx.x * 256 + threadIdx.x;
  if (i < NV)                    Wvb[i] = (f16)Wv[i];
  else if (i < NV + NQ)          WQKb[i - NV] = (f16)Wq[i - NV];
  else if (i < NV + 2 * NQ)      WQKb[i - NV] = (f16)Wk[i - NV - NQ];
  else if (i < NV + 2 * NQ + 2 * DD) {
    int t = i - NV - 2 * NQ;
    bqk[t] = (t < DD) ? bq[t] : bk[t - DD];
  }
}

// ---------------- transpose + f32->f16 for x and x1; 64x64 tiles, half8 stores ----------------
__global__ __launch_bounds__(256)
void transpose_cvt(const float* __restrict__ x, const float* __restrict__ x1,
                   f16* __restrict__ ox, f16* __restrict__ ox1, int nb)
{
  const int zz = blockIdx.z;
  const int b  = (zz < nb) ? zz : zz - nb;
  const float* in = ((zz < nb) ? x : x1) + (size_t)b * CC * NNN;
  f16* out = ((zz < nb) ? ox : ox1) + (size_t)b * CC * NNN;
  __shared__ float tile[64][65];
  const int c0 = blockIdx.y * 64;
  const int n0 = blockIdx.x * 64;
  const int t  = threadIdx.x;
  const int rn = (t & 15) * 4;
  const int rc = t >> 4;
#pragma unroll
  for (int r = 0; r < 4; ++r) {
    const float4 v = *(const float4*)(in + (size_t)(c0 + rc + r * 16) * NNN + n0 + rn);
    tile[rc + r * 16][rn]     = v.x;
    tile[rc + r * 16][rn + 1] = v.y;
    tile[rc + r * 16][rn + 2] = v.z;
    tile[rc + r * 16][rn + 3] = v.w;
  }
  __syncthreads();
  const int ce = (t & 7) * 8;
  const int nr = t >> 3;
#pragma unroll
  for (int r = 0; r < 2; ++r) {
    half8 vv;
#pragma unroll
    for (int e = 0; e < 8; ++e) vv[e] = (f16)tile[ce + e][nr + r * 32];
    *(half8*)(out + (size_t)(n0 + nr + r * 32) * CC + c0 + ce) = vv;
  }
}

// ---------------- per-row mean + max (f16 input); grid (CC, nbatch) ----------------
__global__ __launch_bounds__(256)
void rowreduce(const f16* __restrict__ X, float* __restrict__ avg, float* __restrict__ mx, int ncols)
{
  const size_t ridx = (size_t)blockIdx.y * gridDim.x + blockIdx.x;
  const half8* p = (const half8*)(X + ridx * ncols);
  float s = 0.f, m = -3.402823466e38f;
  for (int i = threadIdx.x; i < ncols / 8; i += 256) {
    half8 v = p[i];
#pragma unroll
    for (int e = 0; e < 8; ++e) {
      float f = (float)v[e];
      s += f;
      m = fmaxf(m, f);
    }
  }
#pragma unroll
  for (int o = 32; o > 0; o >>= 1) {
    s += __shfl_down(s, o);
    m = fmaxf(m, __shfl_down(m, o));
  }
  __shared__ float ss[4], sm[4];
  if ((threadIdx.x & 63) == 0) { ss[threadIdx.x >> 6] = s; sm[threadIdx.x >> 6] = m; }
  __syncthreads();
  if (threadIdx.x == 0) {
    s = ss[0] + ss[1] + ss[2] + ss[3];
    m = fmaxf(fmaxf(sm[0], sm[1]), fmaxf(sm[2], sm[3]));
    avg[ridx] = s / (float)ncols;
    mx[ridx] = m;
  }
}

// ---------------- CBAM MLP gate; grid (nbatch) ----------------
__global__ __launch_bounds__(256)
void mlp_gate(const float* __restrict__ avg, const float* __restrict__ mxv,
              const float* __restrict__ W1, const float* __restrict__ W2,
              float* __restrict__ gate)
{
  const int z = blockIdx.x;
  avg += (size_t)z * CC; mxv += (size_t)z * CC; gate += (size_t)z * CC;
  const int t = threadIdx.x;
  const int r = t & 63;
  const int part = t >> 6;
  __shared__ float pa[4][64], pm[4][64], h[RRR];
  {
    const float* w = W1 + (size_t)r * CC + part * 256;
    const float* av = avg + part * 256;
    const float* mv = mxv + part * 256;
    float sa = 0.f, sm = 0.f;
    for (int c = 0; c < 256; ++c) { float wv = w[c]; sa += wv * av[c]; sm += wv * mv[c]; }
    pa[part][r] = sa; pm[part][r] = sm;
  }
  __syncthreads();
  if (t < RRR) {
    float A_ = pa[0][t] + pa[1][t] + pa[2][t] + pa[3][t];
    float M_ = pm[0][t] + pm[1][t] + pm[2][t] + pm[3][t];
    h[t] = fmaxf(A_, 0.f) + fmaxf(M_, 0.f);
  }
  __syncthreads();
  for (int c = t; c < CC; c += 256) {
    float s = 0.f;
    for (int rr = 0; rr < RRR; ++rr) s += W2[(size_t)c * RRR + rr] * h[rr];
    gate[c] = 1.0f / (1.0f + __expf(-s));
  }
}

// ---------------- apply gate: f16 in -> f32 out; grid (CC*NNN/8/256, nbatch) ----------------
__global__ __launch_bounds__(256)
void scale_out(const f16* __restrict__ oh, float* __restrict__ out, const float* __restrict__ gate)
{
  oh  += (size_t)blockIdx.y * CC * NNN;
  out += (size_t)blockIdx.y * CC * NNN;
  gate += (size_t)blockIdx.y * CC;
  size_t i = (size_t)blockIdx.x * 256 + threadIdx.x;   // over C*N/8
  half8 v = ((const half8*)oh)[i];
  const float g = gate[(i * 8) >> 12];                 // N = 4096
  float4 a = { (float)v[0] * g, (float)v[1] * g, (float)v[2] * g, (float)v[3] * g };
  float4 b = { (float)v[4] * g, (float)v[5] * g, (float)v[6] * g, (float)v[7] * g };
  float4* o = (float4*)out;
  o[2 * i]     = a;
  o[2 * i + 1] = b;
}

// ---------------- launch ----------------
extern "C" void kernel_launch(void* const* d_in, const int* in_sizes, int n_in,
                              void* d_out, int out_size, void* d_ws, size_t ws_size,
                              hipStream_t stream)
{
  const float* x    = (const float*)d_in[0];
  const float* x1   = (const float*)d_in[1];
  const float* Wq   = (const float*)d_in[2];
  const float* bq   = (const float*)d_in[3];
  const float* Wk   = (const float*)d_in[4];
  const float* bk   = (const float*)d_in[5];
  const float* Wv   = (const float*)d_in[6];
  const float* bv   = (const float*)d_in[7];
  const float* Wca1 = (const float*)d_in[8];
  const float* Wca2 = (const float*)d_in[9];
  float* out = (float*)d_out;

  char* ws = (char*)d_ws;
  size_t off = 0;
  auto alloc = [&](size_t bytes) { void* p = ws + off; off += (bytes + 255) & ~255ULL; return p; };

  f16* WQKb = (f16*)alloc((size_t)2 * DD * CC * 2);
  f16* Wvb  = (f16*)alloc((size_t)CC * CC * 2);
  float* bqk  = (float*)alloc(256 * 4);
  float* avg  = (float*)alloc((size_t)BBATCH * CC * 4);
  float* mxv  = (float*)alloc((size_t)BBATCH * CC * 4);
  float* gate = (float*)alloc((size_t)BBATCH * CC * 4);

  const size_t attB = (size_t)NNN * NNN * 2;              // 32 MiB / batch
  const size_t xTB  = (size_t)BBATCH * NNN * CC * 2;      // 32 MiB
  const size_t qkB  = (size_t)BBATCH * NNN * 2 * DD * 2;  // 8 MiB
  const size_t vBB  = (size_t)BBATCH * CC * NNN * 2;      // 32 MiB
  const size_t ohB  = (size_t)BBATCH * CC * NNN * 2;      // 32 MiB
  const size_t fixedEnd = off;

  const dim3 blk(256);
  const int prepN = CC * CC + 2 * DD * CC + 2 * DD;
  prep<<<(prepN + 255) / 256, blk, 0, stream>>>(Wq, Wk, Wv, bq, bk, WQKb, Wvb, bqk);

  // ---------- fast path: all 4 batches in one pass; att (128 MiB) overlays the dead
  // ---------- xT buffers, so the footprint (200 MiB) equals the old g=2 layout.
  {
    size_t offF = fixedEnd;
    auto af_ = [&](size_t bytes) { void* p = ws + offF; offF += (bytes + 255) & ~255ULL; return p; };
    f16* QKt  = (f16*)af_(qkB);                    // [b][n][256] : 0..127 = Q, 128..255 = K
    f16* Vb   = (f16*)af_(vBB);                    // [b][c][m]
    f16* outh = (f16*)af_(ohB);                    // [b][c][n] f16
    f16* att  = (f16*)af_((size_t)BBATCH * attB);  // [b][n][m]; first 64 MiB doubles as xT
    if (offF + (1 << 20) <= ws_size) {
      f16* xTb  = att;                              // [b][n][c]
      f16* x1Tb = att + (size_t)BBATCH * NNN * CC;  // [b][n][c]

      transpose_cvt<<<dim3(NNN / 64, CC / 64, 2 * BBATCH), blk, 0, stream>>>(x, x1, xTb, x1Tb, BBATCH);

      gemm_bt<2><<<dim3(2 * DD / BN, NNN / BM, BBATCH), blk, 0, stream>>>(
          xTb, WQKb, QKt, bqk, 2 * DD, CC,
          CC, CC, 2 * DD, (size_t)NNN * CC, 0, (size_t)NNN * 2 * DD);
      gemm8p<1><<<dim3(NNN / 256, CC / 256, BBATCH), dim3(512), 0, stream>>>(
          Wvb, x1Tb, Vb, bv, CC,
          CC, CC, NNN, 0, (size_t)NNN * CC, (size_t)CC * NNN);

      const size_t sQK = (size_t)NNN * 2 * DD;
      gemm8p<3><<<dim3(NNN / 256, NNN / 256, BBATCH), dim3(512), 0, stream>>>(
          QKt, QKt + DD, att, nullptr, DD,
          2 * DD, 2 * DD, NNN, sQK, sQK, (size_t)NNN * NNN);
      gemm8p<0><<<dim3(NNN / 256, CC / 256, BBATCH), dim3(512), 0, stream>>>(
          Vb, att, outh, nullptr, NNN,
          NNN, NNN, NNN, (size_t)CC * NNN, (size_t)NNN * NNN, (size_t)CC * NNN);

      rowreduce<<<dim3(CC, BBATCH), blk, 0, stream>>>(outh, avg, mxv, NNN);
      mlp_gate<<<BBATCH, blk, 0, stream>>>(avg, mxv, Wca1, Wca2, gate);
      scale_out<<<dim3(CC * NNN / 8 / 256, BBATCH), blk, 0, stream>>>(outh, out, gate);
      return;
    }
  }

  // ---------- fallback: original staged layout ----------
  int g = 0;
  for (int cand = BBATCH; cand >= 1; cand >>= 1) {
    size_t need = fixedEnd + 2 * xTB + qkB + vBB + ohB + (size_t)cand * attB + (1 << 20);
    if (need <= ws_size) { g = cand; break; }
  }

  if (g > 0) {
    f16* xTb  = (f16*)alloc(xTB);
    f16* x1Tb = (f16*)alloc(xTB);
    f16* QKt  = (f16*)alloc(qkB);
    f16* Vb   = (f16*)alloc(vBB);
    f16* outh = (f16*)alloc(ohB);
    f16* att  = (f16*)alloc((size_t)g * attB);

    transpose_cvt<<<dim3(NNN / 64, CC / 64, 2 * BBATCH), blk, 0, stream>>>(x, x1, xTb, x1Tb, BBATCH);

    gemm_bt<2><<<dim3(2 * DD / BN, NNN / BM, BBATCH), blk, 0, stream>>>(
        xTb, WQKb, QKt, bqk, 2 * DD, CC,
        CC, CC, 2 * DD, (size_t)NNN * CC, 0, (size_t)NNN * 2 * DD);
    gemm_bt<1><<<dim3(NNN / BN, CC / BM, BBATCH), blk, 0, stream>>>(
        Wvb, x1Tb, Vb, bv, NNN, CC,
        CC, CC, NNN, 0, (size_t)NNN * CC, (size_t)CC * NNN);

    for (int b0 = 0; b0 < BBATCH; b0 += g) {
      const int gc = (b0 + g <= BBATCH) ? g : (BBATCH - b0);
      const size_t sQK = (size_t)NNN * 2 * DD;
      gemm_bt<3><<<dim3(NNN / BN, NNN / BM, gc), blk, 0, stream>>>(
          QKt + (size_t)b0 * sQK, QKt + (size_t)b0 * sQK + DD, att, nullptr,
          NNN, DD, 2 * DD, 2 * DD, NNN, sQK, sQK, (size_t)NNN * NNN);
      gemm_bt<0><<<dim3(NNN / BN, CC / BM, gc), blk, 0, stream>>>(
          Vb + (size_t)b0 * CC * NNN, att, outh + (size_t)b0 * CC * NNN, nullptr,
          NNN, NNN, NNN, NNN, NNN,
          (size_t)CC * NNN, (size_t)NNN * NNN, (size_t)CC * NNN);
    }

    rowreduce<<<dim3(CC, BBATCH), blk, 0, stream>>>(outh, avg, mxv, NNN);
    mlp_gate<<<BBATCH, blk, 0, stream>>>(avg, mxv, Wca1, Wca2, gate);
    scale_out<<<dim3(CC * NNN / 8 / 256, BBATCH), blk, 0, stream>>>(outh, out, gate);
  } else {
    // legacy per-batch mode (ws-constrained fallback)
    f16* xTb  = (f16*)alloc((size_t)NNN * CC * 2);
    f16* x1Tb = (f16*)alloc((size_t)NNN * CC * 2);
    f16* QKt  = (f16*)alloc((size_t)NNN * 2 * DD * 2);
    f16* Vb   = (f16*)alloc((size_t)CC * NNN * 2);
    f16* outh = (f16*)alloc((size_t)CC * NNN * 2);
    f16* att  = (f16*)alloc(attB);

    for (int b = 0; b < BBATCH; ++b) {
      const float* xb  = x  + (size_t)b * CC * NNN;
      const float* x1b = x1 + (size_t)b * CC * NNN;
      float* outb = out + (size_t)b * CC * NNN;

      transpose_cvt<<<dim3(NNN / 64, CC / 64, 2), blk, 0, stream>>>(xb, x1b, xTb, x1Tb, 1);

      gemm_bt<2><<<dim3(2 * DD / BN, NNN / BM, 1), blk, 0, stream>>>(
          xTb, WQKb, QKt, bqk, 2 * DD, CC, CC, CC, 2 * DD, 0, 0, 0);
      gemm_bt<1><<<dim3(NNN / BN, CC / BM, 1), blk, 0, stream>>>(
          Wvb, x1Tb, Vb, bv, NNN, CC, CC, CC, NNN, 0, 0, 0);
      gemm_bt<3><<<dim3(NNN / BN, NNN / BM, 1), blk, 0, stream>>>(
          QKt, QKt + DD, att, nullptr, NNN, DD, 2 * DD, 2 * DD, NNN, 0, 0, 0);
      gemm_bt<0><<<dim3(NNN / BN, CC / BM, 1), blk, 0, stream>>>(
          Vb, att, outh, nullptr, NNN, NNN, NNN, NNN, NNN, 0, 0, 0);

      rowreduce<<<dim3(CC, 1), blk, 0, stream>>>(outh, avg + (size_t)b * CC, mxv + (size_t)b * CC, NNN);
      mlp_gate<<<1, blk, 0, stream>>>(avg + (size_t)b * CC, mxv + (size_t)b * CC, Wca1, Wca2, gate + (size_t)b * CC);
      scale_out<<<dim3(CC * NNN / 8 / 256, 1), blk, 0, stream>>>(outh, outb, gate + (size_t)b * CC);
    }
  }
}

// Round 4
// 475.555 us; speedup vs baseline: 1.0204x; 1.0204x over previous
//
#include <hip/hip_runtime.h>
#include <hip/hip_fp16.h>
#include <cstdint>

typedef _Float16 f16;
typedef __attribute__((ext_vector_type(8))) _Float16 half8;
typedef __attribute__((ext_vector_type(4))) float floatx4;
typedef __attribute__((ext_vector_type(16))) float floatx16;

#define CC 1024
#define DD 128
#define RRR 64
#define BBATCH 4
#define NNN 4096   // H*W

#define BM 128
#define BN 128
#define BK 64

__device__ __forceinline__ void gl_lds16(const void* g, void* l) {
  __builtin_amdgcn_global_load_lds(
      (__attribute__((address_space(1))) void*)(uintptr_t)g,
      (__attribute__((address_space(3))) void*)l, 16, 0, 0);
}

// ---------------- GEMM: C[M,N] = A[M,K] * B[N,K]^T  (f16 in, f32 acc, f16 out) ----------------
// 128x128 tile, 4 waves, m97-style single-buffer structure (~900 TF ceiling).
// Kept for: QK-proj (small N) and ws-constrained fallback.
template<int EPI>
__global__ __launch_bounds__(256)
void gemm_bt(const f16* __restrict__ A, const f16* __restrict__ Bp, f16* __restrict__ Cout,
             const float* __restrict__ bias, int N, int K,
             int lda, int ldb, int ldc, size_t sA, size_t sB, size_t sC)
{
  __shared__ __align__(16) f16 S[2 * BM * BK];      // 32 KiB
  f16* As = S;
  f16* Bs = S + BM * BK;

  const int z = blockIdx.z;
  const int tid  = threadIdx.x;
  const int lane = tid & 63;
  const int wave = tid >> 6;
  const int m0 = blockIdx.y * BM;
  const int n0 = blockIdx.x * BN;
  const int wm = (wave >> 1) * 64;
  const int wn = (wave & 1) * 64;
  const int l31 = lane & 31;
  const int hi  = lane >> 5;
  const int rs  = lane & 7;

  const f16* Ab = A  + (size_t)z * sA + (size_t)m0 * lda;
  const f16* Bb = Bp + (size_t)z * sB + (size_t)n0 * ldb;

  floatx16 acc[2][2];
#pragma unroll
  for (int i = 0; i < 2; ++i)
#pragma unroll
    for (int j = 0; j < 2; ++j)
#pragma unroll
      for (int r = 0; r < 16; ++r)
        acc[i][j][r] = 0.f;

  int srow[4], ssrc[4];
#pragma unroll
  for (int r = 0; r < 4; ++r) {
    const int gi = r * 256 + tid;
    const int row = gi >> 3;
    const int gc  = gi & 7;
    srow[r] = row;
    ssrc[r] = ((gc ^ (row & 7)) << 3);
  }

  for (int k0 = 0; k0 < K; k0 += BK) {
#pragma unroll
    for (int r = 0; r < 4; ++r) {
      gl_lds16(Ab + (size_t)srow[r] * lda + k0 + ssrc[r], As + (size_t)(r * 256 + tid) * 8);
      gl_lds16(Bb + (size_t)srow[r] * ldb + k0 + ssrc[r], Bs + (size_t)(r * 256 + tid) * 8);
    }
    __syncthreads();

#pragma unroll
    for (int kk = 0; kk < BK; kk += 16) {
      const int gr = (((kk >> 3) + hi) ^ rs) << 3;
      half8 af[2], bfr[2];
#pragma unroll
      for (int i = 0; i < 2; ++i)
        af[i] = *(const half8*)(As + (wm + i * 32 + l31) * BK + gr);
#pragma unroll
      for (int j = 0; j < 2; ++j)
        bfr[j] = *(const half8*)(Bs + (wn + j * 32 + l31) * BK + gr);
#pragma unroll
      for (int i = 0; i < 2; ++i)
#pragma unroll
        for (int j = 0; j < 2; ++j)
          acc[i][j] = __builtin_amdgcn_mfma_f32_32x32x16_f16(af[i], bfr[j], acc[i][j], 0, 0, 0);
    }
    __syncthreads();
  }

  // epilogue: repack through LDS (granule-swizzled), then 16B coalesced stores
  f16* Ch = Cout + (size_t)z * sC;
  f16* Ct = S;   // 128x128 f16 = 32 KiB
#pragma unroll
  for (int i = 0; i < 2; ++i)
#pragma unroll
    for (int j = 0; j < 2; ++j)
#pragma unroll
      for (int r = 0; r < 16; ++r) {
        const int rl = wm + i * 32 + (r & 3) + 8 * (r >> 2) + 4 * hi;
        const int cl = wn + j * 32 + l31;
        const float v = acc[i][j][r];
        f16 h;
        if constexpr (EPI == 0)      h = (f16)v;
        else if constexpr (EPI == 1) h = (f16)(v + bias[m0 + rl]);
        else if constexpr (EPI == 2) h = (f16)(v + bias[n0 + cl]);
        else                         h = (f16)(1.0f / (1.0f + __expf(-v)));
        Ct[rl * BN + ((((cl >> 3) ^ (rl & 7)) << 3) | (cl & 7))] = h;
      }
  __syncthreads();
#pragma unroll
  for (int p = 0; p < 8; ++p) {
    const int idx = p * 256 + tid;
    const int rl = idx >> 4;
    const int g  = idx & 15;
    half8 vv = *(const half8*)(Ct + rl * BN + ((g ^ (rl & 7)) << 3));
    *(half8*)(Ch + (size_t)(m0 + rl) * ldc + n0 + g * 8) = vv;
  }
}

// ---------------- 256x256 / BK=64 double-buffered pipelined GEMM -------------------------------
// C[M,N] = A[M,K]*B[N,K]^T, f16 in / f32 acc / f16 out. 512 threads = 8 waves (2M x 4N),
// per-wave output 128x64 via mfma_f32_16x16x32_f16.
// ROUND-4: drop the intra-tile lockstep barriers (r2/r3 measured 5410 cyc/K-tile = ds_read
// drain + MFMA + writes fully SUMMED; phase barriers exposed the LDS drain then the MFMA
// tail -> MfmaUtil == 621/1466 == 42%, exactly as profiled). Within a tile nothing writes
// buffer `cur`, so reads+MFMAs form ONE region the compiler fine-schedules with counted
// lgkmcnt (m97-verified behavior): later reads drain under earlier MFMAs; the 2 waves/SIMD
// free-run. Only 2 barriers/K-tile remain: (1) post lgkmcnt(0): all waves consumed `cur`
// -> safe to stage t+2 into it; (2) post vmcnt(8): tile t+1 landed (8 loads of t+2 stay in
// flight across it -- never vmcnt(0) in steady state).
#define G8_STAGE(MATG, MIDX, LD, H, KT, BUF) do {                                   \
    gl_lds16(MATG + (size_t)((H) * 128 + srow) * (LD) + (KT) * 64 + soff,           \
             &S[BUF][MIDX][(H) * 8192 + tid * 8]);                                  \
    gl_lds16(MATG + (size_t)((H) * 128 + 64 + srow) * (LD) + (KT) * 64 + soff,      \
             &S[BUF][MIDX][(H) * 8192 + 4096 + tid * 8]);                           \
  } while (0)

#define G8_LDA(DST, MA) do {                                                        \
    _Pragma("unroll") for (int ms = 0; ms < 4; ++ms)                                \
    _Pragma("unroll") for (int ks = 0; ks < 2; ++ks)                                \
      DST[ms * 2 + ks] = *(const half8*)(Ac + aRow + (MA) * 4096 + ms * 1024 + sws[ks]); \
  } while (0)

#define G8_LDB(NH) do {                                                             \
    _Pragma("unroll") for (int ns = 0; ns < 2; ++ns)                                \
    _Pragma("unroll") for (int ks = 0; ks < 2; ++ks)                                \
      bf[NH][ns * 2 + ks] = *(const half8*)(Bc + bRow + (NH) * 2048 + ns * 1024 + sws[ks]); \
  } while (0)

#define G8_MFMA(SRC, MA, NH) do {                                                   \
    __builtin_amdgcn_s_setprio(1);                                                  \
    _Pragma("unroll") for (int ms = 0; ms < 4; ++ms)                                \
    _Pragma("unroll") for (int ns = 0; ns < 2; ++ns)                                \
    _Pragma("unroll") for (int ks = 0; ks < 2; ++ks)                                \
      acc[(MA) * 4 + ms][(NH) * 2 + ns] = __builtin_amdgcn_mfma_f32_16x16x32_f16(   \
          SRC[ms * 2 + ks], bf[NH][ns * 2 + ks], acc[(MA) * 4 + ms][(NH) * 2 + ns], 0, 0, 0); \
    __builtin_amdgcn_s_setprio(0);                                                  \
  } while (0)

template<int EPI>   // 0 = plain, 1 = + row bias, 3 = sigmoid
__global__ __launch_bounds__(512, 2)
void gemm8p(const f16* __restrict__ A, const f16* __restrict__ Bp, f16* __restrict__ Cout,
            const float* __restrict__ bias, int K,
            int lda, int ldb, int ldc, size_t sA, size_t sB, size_t sC)
{
  __shared__ __align__(16) f16 S[2][2][16384];   // 128 KiB

  const int tid  = threadIdx.x;
  const int lane = tid & 63;
  const int wave = tid >> 6;       // 0..7
  const int wm   = wave >> 2;      // 0..1 (M)
  const int wn   = wave & 3;       // 0..3 (N)
  const int l15  = lane & 15;
  const int lk   = lane >> 4;      // 0..3 (k-group)
  const int z    = blockIdx.z;
  const int m0   = blockIdx.y * 256;
  const int n0   = blockIdx.x * 256;

  const f16* Ag = A  + (size_t)z * sA + (size_t)m0 * lda;
  const f16* Bg = Bp + (size_t)z * sB + (size_t)n0 * ldb;

  // staging: thread covers granule tid&7 of row tid>>3 (+64/+128 via H/second load)
  const int srow = tid >> 3;                        // 0..63
  const int soff = (((tid & 7) ^ (srow & 7)) << 3); // pre-swizzled global k-offset (f16 units)

  // ds_read un-swizzle per lane: granule = ks*4 + lk, row&7 = l15&7
  int sws[2];
#pragma unroll
  for (int ks = 0; ks < 2; ++ks) sws[ks] = (((ks * 4 + lk) ^ (l15 & 7)) << 3);
  const int aRow = (wm * 128 + l15) * 64;
  const int bRow = (wn * 64 + l15) * 64;

  floatx4 acc[8][4];
#pragma unroll
  for (int i = 0; i < 8; ++i)
#pragma unroll
    for (int j = 0; j < 4; ++j)
#pragma unroll
      for (int r = 0; r < 4; ++r) acc[i][j][r] = 0.f;

  half8 af[8], a2[8], bf[2][4];

  const int NT = K >> 6;

  // prologue: tiles 0 and 1 fully issued (2-deep prefetch)
  G8_STAGE(Ag, 0, lda, 0, 0, 0);
  G8_STAGE(Bg, 1, ldb, 0, 0, 0);
  G8_STAGE(Ag, 0, lda, 1, 0, 0);
  G8_STAGE(Bg, 1, ldb, 1, 0, 0);
  if (NT > 1) {
    G8_STAGE(Ag, 0, lda, 0, 1, 1);
    G8_STAGE(Bg, 1, ldb, 0, 1, 1);
    G8_STAGE(Ag, 0, lda, 1, 1, 1);
    G8_STAGE(Bg, 1, ldb, 1, 1, 1);
    asm volatile("s_waitcnt vmcnt(8)" ::: "memory");   // tile 0 landed; tile 1 in flight
  } else {
    asm volatile("s_waitcnt vmcnt(0)" ::: "memory");
  }
  __builtin_amdgcn_s_barrier();
  __builtin_amdgcn_sched_barrier(0);

  for (int t = 0; t < NT; ++t) {
    const int cur = t & 1;
    const f16* Ac = &S[cur][0][0];
    const f16* Bc = &S[cur][1][0];

    // one compiler-scheduled region: 24 ds_reads + 64 MFMA, counted lgkm waits auto-inserted.
    // a2 issued after the (0,*) clusters so af's registers can die first (VGPR cap 256).
    G8_LDA(af, 0); G8_LDB(0); G8_LDB(1);
    G8_MFMA(af, 0, 0);
    G8_LDA(a2, 1);
    G8_MFMA(af, 0, 1);
    G8_MFMA(a2, 1, 1);
    G8_MFMA(a2, 1, 0);

    // all of this wave's reads of `cur` done; barrier makes that true block-wide
    asm volatile("s_waitcnt lgkmcnt(0)" ::: "memory");
    __builtin_amdgcn_s_barrier();
    __builtin_amdgcn_sched_barrier(0);

    if (t + 2 < NT) {
      // stage t+2 into cur (now write-safe); wait t+1 landed, t+2 stays in flight
      G8_STAGE(Ag, 0, lda, 0, t + 2, cur);
      G8_STAGE(Bg, 1, ldb, 0, t + 2, cur);
      G8_STAGE(Ag, 0, lda, 1, t + 2, cur);
      G8_STAGE(Bg, 1, ldb, 1, t + 2, cur);
      asm volatile("s_waitcnt vmcnt(8)" ::: "memory");
      __builtin_amdgcn_s_barrier();
      __builtin_amdgcn_sched_barrier(0);
    } else if (t + 1 < NT) {
      asm volatile("s_waitcnt vmcnt(0)" ::: "memory");  // tail: drain t+1
      __builtin_amdgcn_s_barrier();
      __builtin_amdgcn_sched_barrier(0);
    }
    // last tile: barrier above already fenced all LDS reads; epilogue follows
  }

  // epilogue: repack (granule-swizzled) through LDS, 16B coalesced stores
  // C/D 16x16: col = lane&15, row = (lane>>4)*4 + reg  [m89/m91 verified, dtype-indep]
  f16* Ct = &S[0][0][0];   // 256x256 f16 = 128 KiB
  f16* Ch = Cout + (size_t)z * sC;
#pragma unroll
  for (int mi = 0; mi < 8; ++mi)
#pragma unroll
    for (int ni = 0; ni < 4; ++ni)
#pragma unroll
      for (int r = 0; r < 4; ++r) {
        const int rl = wm * 128 + mi * 16 + lk * 4 + r;
        const int cl = wn * 64 + ni * 16 + l15;
        const float v = acc[mi][ni][r];
        f16 h;
        if constexpr (EPI == 1)      h = (f16)(v + bias[m0 + rl]);
        else if constexpr (EPI == 3) h = (f16)(1.0f / (1.0f + __expf(-v)));
        else                         h = (f16)v;
        Ct[rl * 256 + ((((cl >> 3) ^ (rl & 7)) << 3) | (cl & 7))] = h;
      }
  asm volatile("s_waitcnt lgkmcnt(0)" ::: "memory");
  __builtin_amdgcn_s_barrier();
#pragma unroll
  for (int p = 0; p < 16; ++p) {
    const int idx = p * 512 + tid;
    const int rl = idx >> 5;
    const int g  = idx & 31;
    half8 vv = *(const half8*)(Ct + rl * 256 + ((g ^ (rl & 7)) << 3));
    *(half8*)(Ch + (size_t)(m0 + rl) * ldc + n0 + g * 8) = vv;
  }
}

#undef G8_STAGE
#undef G8_LDA
#undef G8_LDB
#undef G8_MFMA

// ---------------- weights f32->f16 + bias concat, one dispatch ----------------
__global__ __launch_bounds__(256)
void prep(const float* __restrict__ Wq, const float* __restrict__ Wk, const float* __restrict__ Wv,
          const float* __restrict__ bq, const float* __restrict__ bk,
          f16* __restrict__ WQKb, f16* __restrict__ Wvb, float* __restrict__ bqk)
{
  const int NV = CC * CC;
  const int NQ = DD * CC;
  int i = blockIdx.x * 256 + threadIdx.x;
  if (i < NV)                    Wvb[i] = (f16)Wv[i];
  else if (i < NV + NQ)          WQKb[i - NV] = (f16)Wq[i - NV];
  else if (i < NV + 2 * NQ)      WQKb[i - NV] = (f16)Wk[i - NV - NQ];
  else if (i < NV + 2 * NQ + 2 * DD) {
    int t = i - NV - 2 * NQ;
    bqk[t] = (t < DD) ? bq[t] : bk[t - DD];
  }
}

// ---------------- transpose + f32->f16 for x and x1; 64x64 tiles, half8 stores ----------------
__global__ __launch_bounds__(256)
void transpose_cvt(const float* __restrict__ x, const float* __restrict__ x1,
                   f16* __restrict__ ox, f16* __restrict__ ox1, int nb)
{
  const int zz = blockIdx.z;
  const int b  = (zz < nb) ? zz : zz - nb;
  const float* in = ((zz < nb) ? x : x1) + (size_t)b * CC * NNN;
  f16* out = ((zz < nb) ? ox : ox1) + (size_t)b * CC * NNN;
  __shared__ float tile[64][65];
  const int c0 = blockIdx.y * 64;
  const int n0 = blockIdx.x * 64;
  const int t  = threadIdx.x;
  const int rn = (t & 15) * 4;
  const int rc = t >> 4;
#pragma unroll
  for (int r = 0; r < 4; ++r) {
    const float4 v = *(const float4*)(in + (size_t)(c0 + rc + r * 16) * NNN + n0 + rn);
    tile[rc + r * 16][rn]     = v.x;
    tile[rc + r * 16][rn + 1] = v.y;
    tile[rc + r * 16][rn + 2] = v.z;
    tile[rc + r * 16][rn + 3] = v.w;
  }
  __syncthreads();
  const int ce = (t & 7) * 8;
  const int nr = t >> 3;
#pragma unroll
  for (int r = 0; r < 2; ++r) {
    half8 vv;
#pragma unroll
    for (int e = 0; e < 8; ++e) vv[e] = (f16)tile[ce + e][nr + r * 32];
    *(half8*)(out + (size_t)(n0 + nr + r * 32) * CC + c0 + ce) = vv;
  }
}

// ---------------- per-row mean + max (f16 input); grid (CC, nbatch) ----------------
__global__ __launch_bounds__(256)
void rowreduce(const f16* __restrict__ X, float* __restrict__ avg, float* __restrict__ mx, int ncols)
{
  const size_t ridx = (size_t)blockIdx.y * gridDim.x + blockIdx.x;
  const half8* p = (const half8*)(X + ridx * ncols);
  float s = 0.f, m = -3.402823466e38f;
  for (int i = threadIdx.x; i < ncols / 8; i += 256) {
    half8 v = p[i];
#pragma unroll
    for (int e = 0; e < 8; ++e) {
      float f = (float)v[e];
      s += f;
      m = fmaxf(m, f);
    }
  }
#pragma unroll
  for (int o = 32; o > 0; o >>= 1) {
    s += __shfl_down(s, o);
    m = fmaxf(m, __shfl_down(m, o));
  }
  __shared__ float ss[4], sm[4];
  if ((threadIdx.x & 63) == 0) { ss[threadIdx.x >> 6] = s; sm[threadIdx.x >> 6] = m; }
  __syncthreads();
  if (threadIdx.x == 0) {
    s = ss[0] + ss[1] + ss[2] + ss[3];
    m = fmaxf(fmaxf(sm[0], sm[1]), fmaxf(sm[2], sm[3]));
    avg[ridx] = s / (float)ncols;
    mx[ridx] = m;
  }
}

// ---------------- CBAM MLP gate; grid (nbatch) ----------------
__global__ __launch_bounds__(256)
void mlp_gate(const float* __restrict__ avg, const float* __restrict__ mxv,
              const float* __restrict__ W1, const float* __restrict__ W2,
              float* __restrict__ gate)
{
  const int z = blockIdx.x;
  avg += (size_t)z * CC; mxv += (size_t)z * CC; gate += (size_t)z * CC;
  const int t = threadIdx.x;
  const int r = t & 63;
  const int part = t >> 6;
  __shared__ float pa[4][64], pm[4][64], h[RRR];
  {
    const float* w = W1 + (size_t)r * CC + part * 256;
    const float* av = avg + part * 256;
    const float* mv = mxv + part * 256;
    float sa = 0.f, sm = 0.f;
    for (int c = 0; c < 256; ++c) { float wv = w[c]; sa += wv * av[c]; sm += wv * mv[c]; }
    pa[part][r] = sa; pm[part][r] = sm;
  }
  __syncthreads();
  if (t < RRR) {
    float A_ = pa[0][t] + pa[1][t] + pa[2][t] + pa[3][t];
    float M_ = pm[0][t] + pm[1][t] + pm[2][t] + pm[3][t];
    h[t] = fmaxf(A_, 0.f) + fmaxf(M_, 0.f);
  }
  __syncthreads();
  for (int c = t; c < CC; c += 256) {
    float s = 0.f;
    for (int rr = 0; rr < RRR; ++rr) s += W2[(size_t)c * RRR + rr] * h[rr];
    gate[c] = 1.0f / (1.0f + __expf(-s));
  }
}

// ---------------- apply gate: f16 in -> f32 out; grid (CC*NNN/8/256, nbatch) ----------------
__global__ __launch_bounds__(256)
void scale_out(const f16* __restrict__ oh, float* __restrict__ out, const float* __restrict__ gate)
{
  oh  += (size_t)blockIdx.y * CC * NNN;
  out += (size_t)blockIdx.y * CC * NNN;
  gate += (size_t)blockIdx.y * CC;
  size_t i = (size_t)blockIdx.x * 256 + threadIdx.x;   // over C*N/8
  half8 v = ((const half8*)oh)[i];
  const float g = gate[(i * 8) >> 12];                 // N = 4096
  float4 a = { (float)v[0] * g, (float)v[1] * g, (float)v[2] * g, (float)v[3] * g };
  float4 b = { (float)v[4] * g, (float)v[5] * g, (float)v[6] * g, (float)v[7] * g };
  float4* o = (float4*)out;
  o[2 * i]     = a;
  o[2 * i + 1] = b;
}

// ---------------- launch ----------------
extern "C" void kernel_launch(void* const* d_in, const int* in_sizes, int n_in,
                              void* d_out, int out_size, void* d_ws, size_t ws_size,
                              hipStream_t stream)
{
  const float* x    = (const float*)d_in[0];
  const float* x1   = (const float*)d_in[1];
  const float* Wq   = (const float*)d_in[2];
  const float* bq   = (const float*)d_in[3];
  const float* Wk   = (const float*)d_in[4];
  const float* bk   = (const float*)d_in[5];
  const float* Wv   = (const float*)d_in[6];
  const float* bv   = (const float*)d_in[7];
  const float* Wca1 = (const float*)d_in[8];
  const float* Wca2 = (const float*)d_in[9];
  float* out = (float*)d_out;

  char* ws = (char*)d_ws;
  size_t off = 0;
  auto alloc = [&](size_t bytes) { void* p = ws + off; off += (bytes + 255) & ~255ULL; return p; };

  f16* WQKb = (f16*)alloc((size_t)2 * DD * CC * 2);
  f16* Wvb  = (f16*)alloc((size_t)CC * CC * 2);
  float* bqk  = (float*)alloc(256 * 4);
  float* avg  = (float*)alloc((size_t)BBATCH * CC * 4);
  float* mxv  = (float*)alloc((size_t)BBATCH * CC * 4);
  float* gate = (float*)alloc((size_t)BBATCH * CC * 4);

  const size_t attB = (size_t)NNN * NNN * 2;              // 32 MiB / batch
  const size_t xTB  = (size_t)BBATCH * NNN * CC * 2;      // 32 MiB
  const size_t qkB  = (size_t)BBATCH * NNN * 2 * DD * 2;  // 8 MiB
  const size_t vBB  = (size_t)BBATCH * CC * NNN * 2;      // 32 MiB
  const size_t ohB  = (size_t)BBATCH * CC * NNN * 2;      // 32 MiB
  const size_t fixedEnd = off;

  const dim3 blk(256);
  const int prepN = CC * CC + 2 * DD * CC + 2 * DD;
  prep<<<(prepN + 255) / 256, blk, 0, stream>>>(Wq, Wk, Wv, bq, bk, WQKb, Wvb, bqk);

  // ---------- fast path: all 4 batches in one pass; att (128 MiB) overlays the dead
  // ---------- xT buffers, so the footprint (200 MiB) equals the old g=2 layout.
  {
    size_t offF = fixedEnd;
    auto af_ = [&](size_t bytes) { void* p = ws + offF; offF += (bytes + 255) & ~255ULL; return p; };
    f16* QKt  = (f16*)af_(qkB);                    // [b][n][256] : 0..127 = Q, 128..255 = K
    f16* Vb   = (f16*)af_(vBB);                    // [b][c][m]
    f16* outh = (f16*)af_(ohB);                    // [b][c][n] f16
    f16* att  = (f16*)af_((size_t)BBATCH * attB);  // [b][n][m]; first 64 MiB doubles as xT
    if (offF + (1 << 20) <= ws_size) {
      f16* xTb  = att;                              // [b][n][c]
      f16* x1Tb = att + (size_t)BBATCH * NNN * CC;  // [b][n][c]

      transpose_cvt<<<dim3(NNN / 64, CC / 64, 2 * BBATCH), blk, 0, stream>>>(x, x1, xTb, x1Tb, BBATCH);

      gemm_bt<2><<<dim3(2 * DD / BN, NNN / BM, BBATCH), blk, 0, stream>>>(
          xTb, WQKb, QKt, bqk, 2 * DD, CC,
          CC, CC, 2 * DD, (size_t)NNN * CC, 0, (size_t)NNN * 2 * DD);
      gemm8p<1><<<dim3(NNN / 256, CC / 256, BBATCH), dim3(512), 0, stream>>>(
          Wvb, x1Tb, Vb, bv, CC,
          CC, CC, NNN, 0, (size_t)NNN * CC, (size_t)CC * NNN);

      const size_t sQK = (size_t)NNN * 2 * DD;
      gemm8p<3><<<dim3(NNN / 256, NNN / 256, BBATCH), dim3(512), 0, stream>>>(
          QKt, QKt + DD, att, nullptr, DD,
          2 * DD, 2 * DD, NNN, sQK, sQK, (size_t)NNN * NNN);
      gemm8p<0><<<dim3(NNN / 256, CC / 256, BBATCH), dim3(512), 0, stream>>>(
          Vb, att, outh, nullptr, NNN,
          NNN, NNN, NNN, (size_t)CC * NNN, (size_t)NNN * NNN, (size_t)CC * NNN);

      rowreduce<<<dim3(CC, BBATCH), blk, 0, stream>>>(outh, avg, mxv, NNN);
      mlp_gate<<<BBATCH, blk, 0, stream>>>(avg, mxv, Wca1, Wca2, gate);
      scale_out<<<dim3(CC * NNN / 8 / 256, BBATCH), blk, 0, stream>>>(outh, out, gate);
      return;
    }
  }

  // ---------- fallback: original staged layout ----------
  int g = 0;
  for (int cand = BBATCH; cand >= 1; cand >>= 1) {
    size_t need = fixedEnd + 2 * xTB + qkB + vBB + ohB + (size_t)cand * attB + (1 << 20);
    if (need <= ws_size) { g = cand; break; }
  }

  if (g > 0) {
    f16* xTb  = (f16*)alloc(xTB);
    f16* x1Tb = (f16*)alloc(xTB);
    f16* QKt  = (f16*)alloc(qkB);
    f16* Vb   = (f16*)alloc(vBB);
    f16* outh = (f16*)alloc(ohB);
    f16* att  = (f16*)alloc((size_t)g * attB);

    transpose_cvt<<<dim3(NNN / 64, CC / 64, 2 * BBATCH), blk, 0, stream>>>(x, x1, xTb, x1Tb, BBATCH);

    gemm_bt<2><<<dim3(2 * DD / BN, NNN / BM, BBATCH), blk, 0, stream>>>(
        xTb, WQKb, QKt, bqk, 2 * DD, CC,
        CC, CC, 2 * DD, (size_t)NNN * CC, 0, (size_t)NNN * 2 * DD);
    gemm_bt<1><<<dim3(NNN / BN, CC / BM, BBATCH), blk, 0, stream>>>(
        Wvb, x1Tb, Vb, bv, NNN, CC,
        CC, CC, NNN, 0, (size_t)NNN * CC, (size_t)CC * NNN);

    for (int b0 = 0; b0 < BBATCH; b0 += g) {
      const int gc = (b0 + g <= BBATCH) ? g : (BBATCH - b0);
      const size_t sQK = (size_t)NNN * 2 * DD;
      gemm_bt<3><<<dim3(NNN / BN, NNN / BM, gc), blk, 0, stream>>>(
          QKt + (size_t)b0 * sQK, QKt + (size_t)b0 * sQK + DD, att, nullptr,
          NNN, DD, 2 * DD, 2 * DD, NNN, sQK, sQK, (size_t)NNN * NNN);
      gemm_bt<0><<<dim3(NNN / BN, CC / BM, gc), blk, 0, stream>>>(
          Vb + (size_t)b0 * CC * NNN, att, outh + (size_t)b0 * CC * NNN, nullptr,
          NNN, NNN, NNN, NNN, NNN,
          (size_t)CC * NNN, (size_t)NNN * NNN, (size_t)CC * NNN);
    }

    rowreduce<<<dim3(CC, BBATCH), blk, 0, stream>>>(outh, avg, mxv, NNN);
    mlp_gate<<<BBATCH, blk, 0, stream>>>(avg, mxv, Wca1, Wca2, gate);
    scale_out<<<dim3(CC * NNN / 8 / 256, BBATCH), blk, 0, stream>>>(outh, out, gate);
  } else {
    // legacy per-batch mode (ws-constrained fallback)
    f16* xTb  = (f16*)alloc((size_t)NNN * CC * 2);
    f16* x1Tb = (f16*)alloc((size_t)NNN * CC * 2);
    f16* QKt  = (f16*)alloc((size_t)NNN * 2 * DD * 2);
    f16* Vb   = (f16*)alloc((size_t)CC * NNN * 2);
    f16* outh = (f16*)alloc((size_t)CC * NNN * 2);
    f16* att  = (f16*)alloc(attB);

    for (int b = 0; b < BBATCH; ++b) {
      const float* xb  = x  + (size_t)b * CC * NNN;
      const float* x1b = x1 + (size_t)b * CC * NNN;
      float* outb = out + (size_t)b * CC * NNN;

      transpose_cvt<<<dim3(NNN / 64, CC / 64, 2), blk, 0, stream>>>(xb, x1b, xTb, x1Tb, 1);

      gemm_bt<2><<<dim3(2 * DD / BN, NNN / BM, 1), blk, 0, stream>>>(
          xTb, WQKb, QKt, bqk, 2 * DD, CC, CC, CC, 2 * DD, 0, 0, 0);
      gemm_bt<1><<<dim3(NNN / BN, CC / BM, 1), blk, 0, stream>>>(
          Wvb, x1Tb, Vb, bv, NNN, CC, CC, CC, NNN, 0, 0, 0);
      gemm_bt<3><<<dim3(NNN / BN, NNN / BM, 1), blk, 0, stream>>>(
          QKt, QKt + DD, att, nullptr, NNN, DD, 2 * DD, 2 * DD, NNN, 0, 0, 0);
      gemm_bt<0><<<dim3(NNN / BN, CC / BM, 1), blk, 0, stream>>>(
          Vb, att, outh, nullptr, NNN, NNN, NNN, NNN, NNN, 0, 0, 0);

      rowreduce<<<dim3(CC, 1), blk, 0, stream>>>(outh, avg + (size_t)b * CC, mxv + (size_t)b * CC, NNN);
      mlp_gate<<<1, blk, 0, stream>>>(avg + (size_t)b * CC, mxv + (size_t)b * CC, Wca1, Wca2, gate + (size_t)b * CC);
      scale_out<<<dim3(CC * NNN / 8 / 256, 1), blk, 0, stream>>>(outh, outb, gate + (size_t)b * CC);
    }
  }
}